// Round 1
// baseline (826.608 us; speedup 1.0000x reference)
//
#include <hip/hip_runtime.h>
#include <cstdint>

// LWMCrossAttention fused kernel for MI355X (gfx950).
// One block per (batch, window): stage x-window to LDS (bf16, fragment-linear
// chunks), per-wave MFMA projections + register-resident linear attention.
// NOTE: mfma operand type per cdna_hip_programming.md §3: ext_vector_type(8) short
// (bf16 bit patterns). If compile fails wanting <8 x bfloat>, flip V8AB typedef.

typedef short V8AB __attribute__((ext_vector_type(8)));
typedef float V4F  __attribute__((ext_vector_type(4)));

#define IMG_W   256
#define HWSZ    65536       // 256*256
#define CCH     128
#define EPSF    1e-6f

__device__ __forceinline__ unsigned short f2bits(float f) {
    return __builtin_bit_cast(unsigned short, (__bf16)f);   // RNE
}
__device__ __forceinline__ float bits2f(unsigned int h) {
    return __builtin_bit_cast(float, h << 16);
}

// Load one B-operand fragment from a row-major fp32 weight row.
// B[k][n]: n = lane&15 -> weight row o; k = (lane>>4)*8 + j -> 8 consecutive cols.
__device__ __forceinline__ V8AB load_wfrag(const float* __restrict__ wrow) {
    float4 w0 = *(const float4*)(wrow);
    float4 w1 = *(const float4*)(wrow + 4);
    V8AB r;
    r[0] = (short)f2bits(w0.x); r[1] = (short)f2bits(w0.y);
    r[2] = (short)f2bits(w0.z); r[3] = (short)f2bits(w0.w);
    r[4] = (short)f2bits(w1.x); r[5] = (short)f2bits(w1.y);
    r[6] = (short)f2bits(w1.z); r[7] = (short)f2bits(w1.w);
    return r;
}

// Stage a 128ch x 256tok window (fp32, channel-major) into LDS bf16 chunks.
// chunk#(t,c0=8-aligned) = (t>>4)*256 + (c0>>5)*64 + ((c0>>3)&3)*16 + (t&15)
// so that A-frag read for (mt,ks) at lane L is chunk# = mt*256+ks*64+L (lane-linear).
__device__ __forceinline__ void stage_input(const float* __restrict__ src,
                                            short* xbuf, int tid, int pixbase) {
    #pragma unroll
    for (int it = 0; it < 8; ++it) {
        int p  = it * 256 + tid;        // pair id, 0..2047
        int t0 = 2 * (p & 127);         // even token
        int cg = p >> 7;                // channel group 0..15 (8 ch each)
        int c0 = cg * 8;
        const float* g = src + (size_t)c0 * HWSZ + pixbase + (t0 >> 4) * IMG_W + (t0 & 15);
        float2 f[8];
        #pragma unroll
        for (int j = 0; j < 8; ++j)
            f[j] = *(const float2*)(g + (size_t)j * HWSZ);
        V8AB va, vb;
        #pragma unroll
        for (int j = 0; j < 8; ++j) {
            va[j] = (short)f2bits(f[j].x);   // token t0
            vb[j] = (short)f2bits(f[j].y);   // token t0+1
        }
        int ca = ((t0 >> 4) << 8) + ((cg >> 2) << 6) + ((cg & 3) << 4) + (t0 & 15);
        *(V8AB*)(xbuf + (size_t)ca * 8)       = va;
        *(V8AB*)(xbuf + (size_t)(ca + 1) * 8) = vb;
    }
}

__global__ __launch_bounds__(256, 2)
void lwm_fused_kernel(const float* __restrict__ x1, const float* __restrict__ x2,
                      const float* __restrict__ Wq, const float* __restrict__ Wkv,
                      float* __restrict__ out) {
    __shared__ __align__(16) short xbuf[32768];   // 64 KB: 4096 chunks x 16B

    const int tid  = threadIdx.x;
    const int lane = tid & 63;
    const int wv   = tid >> 6;        // wave 0..3, owns heads wv and wv+4
    const int l15  = lane & 15;
    const int quad = lane >> 4;
    const int zhi  = quad >> 1;       // 1 for quads 2,3 (zero K-half of attn mfma)

    const int blk = blockIdx.x;       // b*256 + wy*16 + wx
    const int b   = blk >> 8;
    const int wy  = (blk >> 4) & 15;
    const int wx  = blk & 15;
    const int pixbase = wy * 16 * IMG_W + wx * 16;

    const float* x1b  = x1 + (size_t)b * CCH * HWSZ;
    const float* x2b  = x2 + (size_t)b * CCH * HWSZ;
    float*       outb = out + (size_t)b * CCH * HWSZ;

    // ---------------- stage x1 ----------------
    stage_input(x1b, xbuf, tid, pixbase);
    __syncthreads();

    // ---------------- phase 1: q = x1 . Wq^T, normalize per token ------------
    // qn kept packed bf16 in D-layout: qnp[hh][mt] = {regs 0|1, regs 2|3}
    unsigned int qnp[2][16][2];
    #pragma unroll
    for (int hh = 0; hh < 2; ++hh) {
        const int head = wv + 4 * hh;
        V8AB bq[4];
        #pragma unroll
        for (int ks = 0; ks < 4; ++ks)
            bq[ks] = load_wfrag(Wq + (size_t)(head * 16 + l15) * CCH + ks * 32 + quad * 8);
        #pragma unroll
        for (int mt = 0; mt < 16; ++mt) {
            V4F acc = {0.f, 0.f, 0.f, 0.f};
            #pragma unroll
            for (int ks = 0; ks < 4; ++ks) {
                V8AB a = *(const V8AB*)(xbuf + (size_t)(mt * 256 + ks * 64 + lane) * 8);
                acc = __builtin_amdgcn_mfma_f32_16x16x32_bf16(a, bq[ks], acc, 0, 0, 0);
            }
            // per-token L2 norm over the 16 head-channels (lanes 0..15 of group)
            unsigned int p0 = 0, p1 = 0;
            #pragma unroll
            for (int r = 0; r < 4; ++r) {
                float s = acc[r] * acc[r];
                s += __shfl_xor(s, 1); s += __shfl_xor(s, 2);
                s += __shfl_xor(s, 4); s += __shfl_xor(s, 8);
                float qn = acc[r] * rsqrtf(s);
                unsigned int u = f2bits(qn);
                if      (r == 0) p0  = u;
                else if (r == 1) p0 |= u << 16;
                else if (r == 2) p1  = u;
                else             p1 |= u << 16;
            }
            qnp[hh][mt][0] = p0;
            qnp[hh][mt][1] = p1;
        }
    }
    __syncthreads();

    // ---------------- stage x2 (overwrite) ----------------
    stage_input(x2b, xbuf, tid, pixbase);
    __syncthreads();

    // ---------------- phase 2: k,v projection + linear attention ------------
    #pragma unroll
    for (int hh = 0; hh < 2; ++hh) {
        const int head = wv + 4 * hh;
        V8AB bk[4], bv[4];
        #pragma unroll
        for (int ks = 0; ks < 4; ++ks) {
            bk[ks] = load_wfrag(Wkv + (size_t)(head * 16 + l15) * CCH + ks * 32 + quad * 8);
            bv[ks] = load_wfrag(Wkv + (size_t)(CCH + head * 16 + l15) * CCH + ks * 32 + quad * 8);
        }

        float ksum = 0.f, vsum = 0.f;
        V4F kvacc = {0.f, 0.f, 0.f, 0.f};

        #pragma unroll
        for (int s2 = 0; s2 < 8; ++s2) {     // token-tile pairs (32 tokens)
            V4F aK0 = {0,0,0,0}, aK1 = {0,0,0,0}, aV0 = {0,0,0,0}, aV1 = {0,0,0,0};
            #pragma unroll
            for (int ks = 0; ks < 4; ++ks) {
                V8AB a0 = *(const V8AB*)(xbuf + (size_t)((2*s2    ) * 256 + ks * 64 + lane) * 8);
                V8AB a1 = *(const V8AB*)(xbuf + (size_t)((2*s2 + 1) * 256 + ks * 64 + lane) * 8);
                aK0 = __builtin_amdgcn_mfma_f32_16x16x32_bf16(a0, bk[ks], aK0, 0, 0, 0);
                aV0 = __builtin_amdgcn_mfma_f32_16x16x32_bf16(a0, bv[ks], aV0, 0, 0, 0);
                aK1 = __builtin_amdgcn_mfma_f32_16x16x32_bf16(a1, bk[ks], aK1, 0, 0, 0);
                aV1 = __builtin_amdgcn_mfma_f32_16x16x32_bf16(a1, bv[ks], aV1, 0, 0, 0);
            }
            float kn0[4], kn1[4];
            #pragma unroll
            for (int r = 0; r < 4; ++r) {
                float s = aK0[r] * aK0[r];
                s += __shfl_xor(s, 1); s += __shfl_xor(s, 2);
                s += __shfl_xor(s, 4); s += __shfl_xor(s, 8);
                kn0[r] = aK0[r] * rsqrtf(s);
                float t = aK1[r] * aK1[r];
                t += __shfl_xor(t, 1); t += __shfl_xor(t, 2);
                t += __shfl_xor(t, 4); t += __shfl_xor(t, 8);
                kn1[r] = aK1[r] * rsqrtf(t);
                ksum += kn0[r] + kn1[r];
                vsum += aV0[r] + aV1[r];
            }
            // Build kv_acc operands by quad-shuffle from D-layout regs:
            // A[m=ch=l15][k=token quad*8+j], B[k=token][n=ch=l15]
            V8AB ka, vb;
            #pragma unroll
            for (int j = 0; j < 8; ++j) {
                int src = l15 + ((((quad & 1) * 2) + (j >> 2)) << 4);
                float k0 = __shfl(kn0[j & 3], src);
                float k1 = __shfl(kn1[j & 3], src);
                float v0 = __shfl(aV0[j & 3], src);
                float v1 = __shfl(aV1[j & 3], src);
                ka[j] = (short)f2bits(zhi ? k1 : k0);
                vb[j] = (short)f2bits(zhi ? v1 : v0);
            }
            kvacc = __builtin_amdgcn_mfma_f32_16x16x32_bf16(ka, vb, kvacc, 0, 0, 0);
        }

        // reduce ksum/vsum across quads -> per-lane value for channel l15
        ksum += __shfl_xor(ksum, 16); ksum += __shfl_xor(ksum, 32);
        vsum += __shfl_xor(vsum, 16); vsum += __shfl_xor(vsum, 32);
        const float ksf = ksum + EPSF;

        // kv_acc D-regs -> attn B-frag (K=32, rows 16..31 zero); identity in (n=l15)
        V8AB kvb;
        #pragma unroll
        for (int j = 0; j < 8; ++j) {
            int src = l15 + ((((quad & 1) * 2) + (j >> 2)) << 4);
            float kv = __shfl(kvacc[j & 3], src);
            kvb[j] = zhi ? (short)0 : (short)f2bits(kv);
        }
        // ksf values for channels (quad&1)*8 + j (for the tailor dot)
        float ks8[8];
        #pragma unroll
        for (int j = 0; j < 8; ++j)
            ks8[j] = __shfl(ksf, (quad & 1) * 8 + j);

        #pragma unroll
        for (int mt = 0; mt < 16; ++mt) {
            // Build qn A-frag (x32 layout): lane(l15=token, quad): k=quad*8+j=channel
            unsigned int q0 = qnp[hh][mt][0], q1 = qnp[hh][mt][1];
            V8AB qa;
            float pd = 0.f;
            #pragma unroll
            for (int j = 0; j < 8; ++j) {
                int src = ((quad & 1) * 8 + j) + ((l15 >> 2) << 4);
                unsigned int u0 = __shfl(q0, src);
                unsigned int u1 = __shfl(q1, src);
                unsigned int us = (l15 & 2) ? u1 : u0;
                unsigned int hs = (l15 & 1) ? (us >> 16) : (us & 0xffffu);
                qa[j] = zhi ? (short)0 : (short)hs;
                pd += (zhi ? 0.f : bits2f(hs)) * ks8[j];
            }
            pd += __shfl_xor(pd, 16); pd += __shfl_xor(pd, 32);
            float ta = 1.0f / (256.0f + pd);

            V4F z = {0.f, 0.f, 0.f, 0.f};
            V4F dacc = __builtin_amdgcn_mfma_f32_16x16x32_bf16(qa, kvb, z, 0, 0, 0);

            #pragma unroll
            for (int r = 0; r < 4; ++r) {
                float tl = __shfl(ta, quad * 4 + r);
                float o  = (dacc[r] + vsum) * tl;
                int col  = quad * 4 + r;
                outb[(size_t)(head * 16 + l15) * HWSZ + pixbase + mt * IMG_W + col] = o;
            }
        }
    }
}

extern "C" void kernel_launch(void* const* d_in, const int* in_sizes, int n_in,
                              void* d_out, int out_size, void* d_ws, size_t ws_size,
                              hipStream_t stream) {
    const float* x1  = (const float*)d_in[0];
    const float* x2  = (const float*)d_in[1];
    const float* Wq  = (const float*)d_in[2];
    const float* Wkv = (const float*)d_in[3];
    float* out = (float*)d_out;
    lwm_fused_kernel<<<dim3(2048), dim3(256), 0, stream>>>(x1, x2, Wq, Wkv, out);
}